// Round 1
// baseline (1109.134 us; speedup 1.0000x reference)
//
#include <hip/hip_runtime.h>
#include <hip/hip_bf16.h>
#include <math.h>

#define NEG_SLOPE 0.2f

__device__ __forceinline__ float lrelu(float v) { return v > 0.f ? v : NEG_SLOPE * v; }

// ---------------- CSR build (group edges by dst; self-loops handled inline later) ----------------
__global__ void k_hist(const int* __restrict__ dst, int E, int* __restrict__ cnt) {
    int i = blockIdx.x * blockDim.x + threadIdx.x;
    if (i < E) atomicAdd(&cnt[dst[i]], 1);
}

__global__ void k_scan1(const int* __restrict__ cnt, int N, int* __restrict__ row,
                        int* __restrict__ partials) {
    __shared__ int sh[256];
    int tid = threadIdx.x;
    int i = blockIdx.x * 256 + tid;
    int v = (i < N) ? cnt[i] : 0;
    sh[tid] = v;
    __syncthreads();
    for (int off = 1; off < 256; off <<= 1) {
        int t = (tid >= off) ? sh[tid - off] : 0;
        __syncthreads();
        sh[tid] += t;
        __syncthreads();
    }
    if (i < N) row[i] = sh[tid] - v;      // exclusive within block
    if (tid == 255) partials[blockIdx.x] = sh[255];
}

__global__ void k_scan2(int* __restrict__ partials, int n) {
    __shared__ int sh[512];
    int tid = threadIdx.x;
    int v = (tid < n) ? partials[tid] : 0;
    sh[tid] = v;
    __syncthreads();
    for (int off = 1; off < 512; off <<= 1) {
        int t = (tid >= off) ? sh[tid - off] : 0;
        __syncthreads();
        sh[tid] += t;
        __syncthreads();
    }
    if (tid < n) partials[tid] = sh[tid] - v; // exclusive
}

__global__ void k_scan3(int* __restrict__ row, const int* __restrict__ partials,
                        int* __restrict__ cursor, int N, int E) {
    int i = blockIdx.x * 256 + threadIdx.x;
    if (i < N) {
        int r = row[i] + partials[blockIdx.x];
        row[i] = r;
        cursor[i] = r;
    }
    if (i == 0) row[N] = E;
}

__global__ void k_scatter(const int* __restrict__ src, const int* __restrict__ dst, int E,
                          int* __restrict__ cursor, int* __restrict__ csr_src) {
    int i = blockIdx.x * blockDim.x + threadIdx.x;
    if (i < E) {
        int d = dst[i];
        int pos = atomicAdd(&cursor[d], 1);
        csr_src[pos] = src[i];
    }
}

// ---------------- Layer 1 linear: x[N,10] @ W1[10,64], fused attn dots ----------------
__global__ void k_lin1(const float* __restrict__ x, const float* __restrict__ W,
                       const float* __restrict__ as_, const float* __restrict__ ad_,
                       float* __restrict__ h, float* __restrict__ asc, float* __restrict__ adc,
                       int N) {
    __shared__ float sW[10 * 64];
    int tid = threadIdx.x;
    for (int i = tid; i < 640; i += 256) sW[i] = W[i];
    __syncthreads();
    int wid = tid >> 6, lane = tid & 63;
    int n = blockIdx.x * 4 + wid;
    if (n >= N) return;
    float acc = 0.f;
#pragma unroll
    for (int k = 0; k < 10; ++k) acc += x[n * 10 + k] * sW[k * 64 + lane];
    h[n * 64 + lane] = acc;
    int head = lane >> 5, cc = lane & 31;
    float rs = acc * as_[lane];   // [2,32] flat == [lane]
    float rd = acc * ad_[lane];
#pragma unroll
    for (int m = 16; m >= 1; m >>= 1) {
        rs += __shfl_xor(rs, m, 64);
        rd += __shfl_xor(rd, m, 64);
    }
    if (cc == 0) { asc[n * 2 + head] = rs; adc[n * 2 + head] = rd; }
}

// ---------------- Layers 1/2 linear: y[N,64] @ W[64,64], fused attn dots ----------------
__global__ void k_lin2(const float* __restrict__ yin, const float* __restrict__ W,
                       const float* __restrict__ as_, const float* __restrict__ ad_,
                       float* __restrict__ h, float* __restrict__ asc, float* __restrict__ adc,
                       int N) {
    __shared__ float sW[64 * 64];
    int tid = threadIdx.x;
    for (int i = tid; i < 4096; i += 256) sW[i] = W[i];
    __syncthreads();
    int wid = tid >> 6, lane = tid & 63;
    int n = blockIdx.x * 4 + wid;
    if (n >= N) return;
    float v = yin[n * 64 + lane];
    float acc = 0.f;
#pragma unroll
    for (int k = 0; k < 64; ++k) acc += __shfl(v, k, 64) * sW[k * 64 + lane];
    h[n * 64 + lane] = acc;
    int head = lane >> 5, cc = lane & 31;
    float rs = acc * as_[lane];
    float rd = acc * ad_[lane];
#pragma unroll
    for (int m = 16; m >= 1; m >>= 1) {
        rs += __shfl_xor(rs, m, 64);
        rd += __shfl_xor(rd, m, 64);
    }
    if (cc == 0) { asc[n * 2 + head] = rs; adc[n * 2 + head] = rd; }
}

// ---------------- Aggregate for layers 1,2 (H=2, C=32): wave per dst node ----------------
__global__ void k_agg(const float* __restrict__ h, const float* __restrict__ asc,
                      const float* __restrict__ adc, const int* __restrict__ row,
                      const int* __restrict__ csr_src, const float* __restrict__ bias,
                      float* __restrict__ yout, int N, int do_relu) {
    int tid = threadIdx.x;
    int wid = tid >> 6, lane = tid & 63;
    int n = blockIdx.x * 4 + wid;
    if (n >= N) return;
    int s = row[n], e = row[n + 1];
    int head = lane >> 5;
    float adc0 = adc[n * 2 + 0], adc1 = adc[n * 2 + 1];
    float es0 = lrelu(asc[n * 2 + 0] + adc0);
    float es1 = lrelu(asc[n * 2 + 1] + adc1);
    // Phase A: online softmax (m,z) per head, lanes stride over edges
    float m0 = -1e30f, z0 = 0.f, m1 = -1e30f, z1 = 0.f;
    if (lane == 0) { m0 = es0; z0 = 1.f; m1 = es1; z1 = 1.f; }  // self-loop
    for (int i = s + lane; i < e; i += 64) {
        int src = csr_src[i];
        float e0 = lrelu(asc[src * 2 + 0] + adc0);
        float e1 = lrelu(asc[src * 2 + 1] + adc1);
        if (e0 > m0) { z0 = z0 * __expf(m0 - e0) + 1.f; m0 = e0; } else z0 += __expf(e0 - m0);
        if (e1 > m1) { z1 = z1 * __expf(m1 - e1) + 1.f; m1 = e1; } else z1 += __expf(e1 - m1);
    }
#pragma unroll
    for (int mask = 32; mask >= 1; mask >>= 1) {
        float om0 = __shfl_xor(m0, mask, 64), oz0 = __shfl_xor(z0, mask, 64);
        float om1 = __shfl_xor(m1, mask, 64), oz1 = __shfl_xor(z1, mask, 64);
        float M0 = fmaxf(m0, om0);
        z0 = z0 * __expf(m0 - M0) + oz0 * __expf(om0 - M0); m0 = M0;
        float M1 = fmaxf(m1, om1);
        z1 = z1 * __expf(m1 - M1) + oz1 * __expf(om1 - M1); m1 = M1;
    }
    float mh   = head ? m1 : m0;
    float invz = 1.f / (head ? z1 : z0);
    float adch = head ? adc1 : adc0;
    // Phase B: per-edge coalesced 256B gather of h[src], alpha recomputed per lane
    float acc = 0.f;
    for (int base = s; base < e; base += 64) {
        int idx = base + lane;
        int my_src = (idx < e) ? csr_src[idx] : 0;
        int cnt = min(64, e - base);
        for (int j = 0; j < cnt; ++j) {
            int src = __shfl(my_src, j, 64);
            float alpha = __expf(lrelu(asc[src * 2 + head] + adch) - mh) * invz;
            acc += alpha * h[src * 64 + lane];
        }
    }
    {   // self-loop contribution
        float esh = head ? es1 : es0;
        acc += __expf(esh - mh) * invz * h[n * 64 + lane];
    }
    float yv = acc + bias[lane];
    if (do_relu) yv = fmaxf(yv, 0.f);
    yout[n * 64 + lane] = yv;
}

// ---------------- Layer 3 linear: y[N,64] @ W3[64,4], fused attn dots ----------------
__global__ void k_lin3(const float* __restrict__ yin, const float* __restrict__ W3,
                       const float* __restrict__ a3s, const float* __restrict__ a3d,
                       float* __restrict__ h3, float* __restrict__ asc3, float* __restrict__ adc3,
                       int N) {
    __shared__ float sW[256];
    int tid = threadIdx.x;
    sW[tid] = W3[tid];
    __syncthreads();
    int t = blockIdx.x * 256 + tid;
    int n = t >> 2, c = t & 3;
    if (n >= N) return;
    float acc = 0.f;
#pragma unroll
    for (int k = 0; k < 64; ++k) acc += yin[n * 64 + k] * sW[k * 4 + c];
    h3[n * 4 + c] = acc;
    float rs = acc * a3s[c], rd = acc * a3d[c];
    rs += __shfl_xor(rs, 1, 64); rs += __shfl_xor(rs, 2, 64);
    rd += __shfl_xor(rd, 1, 64); rd += __shfl_xor(rd, 2, 64);
    if (c == 0) { asc3[n] = rs; adc3[n] = rd; }
}

// ---------------- Layer 3 aggregate (H=1, C=4) + sigmoid*100 ----------------
__global__ void k_agg3(const float* __restrict__ h3, const float* __restrict__ asc3,
                       const float* __restrict__ adc3, const int* __restrict__ row,
                       const int* __restrict__ csr_src, const float* __restrict__ b3,
                       float* __restrict__ out, int N) {
    int tid = threadIdx.x;
    int wid = tid >> 6, lane = tid & 63;
    int n = blockIdx.x * 4 + wid;
    if (n >= N) return;
    int s = row[n], e = row[n + 1];
    float adcn = adc3[n];
    float es = lrelu(asc3[n] + adcn);
    float m = -1e30f, z = 0.f;
    if (lane == 0) { m = es; z = 1.f; }
    for (int i = s + lane; i < e; i += 64) {
        float ev = lrelu(asc3[csr_src[i]] + adcn);
        if (ev > m) { z = z * __expf(m - ev) + 1.f; m = ev; } else z += __expf(ev - m);
    }
#pragma unroll
    for (int mask = 32; mask >= 1; mask >>= 1) {
        float om = __shfl_xor(m, mask, 64), oz = __shfl_xor(z, mask, 64);
        float M = fmaxf(m, om);
        z = z * __expf(m - M) + oz * __expf(om - M); m = M;
    }
    float invz = 1.f / z;
    int c = lane & 3, jg = lane >> 2;  // 16 edge-groups x 4 channels
    float acc = 0.f;
    for (int base = s; base < e; base += 16) {
        int idx = base + jg;
        if (idx < e) {
            int src = csr_src[idx];
            float alpha = __expf(lrelu(asc3[src] + adcn) - m) * invz;
            acc += alpha * h3[src * 4 + c];
        }
    }
#pragma unroll
    for (int mask = 4; mask <= 32; mask <<= 1) acc += __shfl_xor(acc, mask, 64);
    if (lane < 4) {
        acc += __expf(es - m) * invz * h3[n * 4 + c];   // self-loop
        float v = acc + b3[c];
        out[n * 4 + c] = 100.f / (1.f + __expf(-v));    // sigmoid * 100
    }
}

extern "C" void kernel_launch(void* const* d_in, const int* in_sizes, int n_in,
                              void* d_out, int out_size, void* d_ws, size_t ws_size,
                              hipStream_t stream) {
    const float* x   = (const float*)d_in[0];
    const int*   ei  = (const int*)d_in[1];
    const float* W1  = (const float*)d_in[2];
    const float* a1s = (const float*)d_in[3];
    const float* a1d = (const float*)d_in[4];
    const float* b1  = (const float*)d_in[5];
    const float* W2  = (const float*)d_in[6];
    const float* a2s = (const float*)d_in[7];
    const float* a2d = (const float*)d_in[8];
    const float* b2  = (const float*)d_in[9];
    const float* W3  = (const float*)d_in[10];
    const float* a3s = (const float*)d_in[11];
    const float* a3d = (const float*)d_in[12];
    const float* b3  = (const float*)d_in[13];
    float* out = (float*)d_out;

    const int N = in_sizes[0] / 10;
    const int E = in_sizes[1] / 2;
    const int* esrc = ei;
    const int* edst = ei + E;

    char* ws = (char*)d_ws;
    size_t off = 0;
    auto alloc = [&](size_t bytes) {
        void* p = ws + off;
        off = (off + bytes + 255) & ~(size_t)255;
        return p;
    };
    int*   row      = (int*)alloc((size_t)(N + 1) * sizeof(int));
    int*   cursor   = (int*)alloc((size_t)N * sizeof(int));       // doubles as cnt
    int*   partials = (int*)alloc(512 * sizeof(int));
    int*   csr      = (int*)alloc((size_t)E * sizeof(int));
    float* h        = (float*)alloc((size_t)N * 64 * sizeof(float));
    float* y        = (float*)alloc((size_t)N * 64 * sizeof(float));
    float* asc      = (float*)alloc((size_t)N * 2 * sizeof(float));
    float* adc      = (float*)alloc((size_t)N * 2 * sizeof(float));
    // layer-3 scratch aliases h (h is dead once lin3 reads y)
    float* h3   = h;
    float* asc3 = h + (size_t)N * 4;
    float* adc3 = h + (size_t)N * 5;

    hipMemsetAsync(cursor, 0, (size_t)N * sizeof(int), stream);

    const int eb = (E + 255) / 256;
    const int nb = (N + 255) / 256;
    const int nw = (N + 3) / 4;  // wave-per-node, 4 waves/block

    k_hist<<<eb, 256, 0, stream>>>(edst, E, cursor);
    k_scan1<<<nb, 256, 0, stream>>>(cursor, N, row, partials);
    k_scan2<<<1, 512, 0, stream>>>(partials, nb);
    k_scan3<<<nb, 256, 0, stream>>>(row, partials, cursor, N, E);
    k_scatter<<<eb, 256, 0, stream>>>(esrc, edst, E, cursor, csr);

    k_lin1<<<nw, 256, 0, stream>>>(x, W1, a1s, a1d, h, asc, adc, N);
    k_agg<<<nw, 256, 0, stream>>>(h, asc, adc, row, csr, b1, y, N, 1);
    k_lin2<<<nw, 256, 0, stream>>>(y, W2, a2s, a2d, h, asc, adc, N);
    k_agg<<<nw, 256, 0, stream>>>(h, asc, adc, row, csr, b2, y, N, 1);
    k_lin3<<<(N * 4 + 255) / 256, 256, 0, stream>>>(y, W3, a3s, a3d, h3, asc3, adc3, N);
    k_agg3<<<nw, 256, 0, stream>>>(h3, asc3, adc3, row, csr, b3, out, N);
}